// Round 2
// baseline (536.989 us; speedup 1.0000x reference)
//
#include <hip/hip_runtime.h>
#include <stdint.h>

#define NN 40000
#define NE 640000
#define ND 128
#define ED 64
#define OD 128
#define KM 192   // ND + ED
#define KA 256   // ND + OD

typedef __attribute__((ext_vector_type(8))) short bf16x8;
typedef __attribute__((ext_vector_type(4))) float f32x4;
typedef __attribute__((ext_vector_type(4))) unsigned short us4;

__device__ __forceinline__ unsigned short f2bf(float f) {
    union { float f; uint32_t u; } v; v.f = f;
    return (unsigned short)((v.u + 0x7fffu + ((v.u >> 16) & 1u)) >> 16);
}
__device__ __forceinline__ us4 pk4(float4 v) {
    us4 r; r.x = f2bf(v.x); r.y = f2bf(v.y); r.z = f2bf(v.z); r.w = f2bf(v.w);
    return r;
}
__device__ __forceinline__ float bfl(uint32_t u) {
    union { uint32_t u; float f; } v; v.u = u << 16; return v.f;
}
__device__ __forceinline__ float bfh(uint32_t u) {
    union { uint32_t u; float f; } v; v.u = u & 0xffff0000u; return v.f;
}

// ---------------- CSR build ----------------
__global__ void hist_kernel(const int* __restrict__ dst, int* __restrict__ cnt) {
    int e = blockIdx.x * blockDim.x + threadIdx.x;
    if (e < NE) atomicAdd(&cnt[dst[e]], 1);
}

// single block, 1024 threads: exclusive scan of cnt[NN] -> off[NN+1], cur = off
__global__ __launch_bounds__(1024) void scan_kernel(
    int* __restrict__ cnt_cur, int* __restrict__ off)
{
    __shared__ int wsum[16];
    __shared__ int carry_s;
    const int t = threadIdx.x;
    if (t == 0) carry_s = 0;
    __syncthreads();
    for (int base = 0; base < NN; base += 1024) {
        int idx = base + t;
        int v = (idx < NN) ? cnt_cur[idx] : 0;
        int x = v;
        #pragma unroll
        for (int d = 1; d < 64; d <<= 1) {
            int y = __shfl_up(x, d, 64);
            if ((t & 63) >= d) x += y;
        }
        int wid = t >> 6;
        if ((t & 63) == 63) wsum[wid] = x;
        __syncthreads();
        if (t < 16) {
            int s = wsum[t];
            #pragma unroll
            for (int d = 1; d < 16; d <<= 1) {
                int y = __shfl_up(s, d, 64);
                if (t >= d) s += y;
            }
            wsum[t] = s;
        }
        __syncthreads();
        int wave_prefix = (wid > 0) ? wsum[wid - 1] : 0;
        int incl = x + wave_prefix + carry_s;
        int excl = incl - v;
        if (idx < NN) { off[idx] = excl; cnt_cur[idx] = excl; }
        __syncthreads();
        if (t == 1023) carry_s = incl;
        __syncthreads();
    }
    if (t == 0) off[NN] = carry_s;
}

__global__ void scatter_kernel(const int* __restrict__ dst,
                               int* __restrict__ cur, int* __restrict__ eid) {
    int e = blockIdx.x * blockDim.x + threadIdx.x;
    if (e < NE) {
        int p = atomicAdd(&cur[dst[e]], 1);
        eid[p] = e;
    }
}

// ---------------- message GEMM -> bf16 msg buffer (no atomics) ----------------
#define MT 32
#define LK (KM + 8)

__global__ __launch_bounds__(256, 2) void msg_kernel(
    const float* __restrict__ node, const float* __restrict__ edgef,
    const int* __restrict__ src,
    const float* __restrict__ Wm, const float* __restrict__ bm,
    unsigned short* __restrict__ msg)
{
    __shared__ unsigned short sW[OD][LK];
    __shared__ unsigned short sA[MT][LK];

    const int t  = threadIdx.x;
    const int e0 = blockIdx.x * MT;

    for (int i = t; i < OD * KM / 4; i += 256) {
        int base = i * 4;
        int n = base / KM, k = base % KM;
        float4 w = *(const float4*)(Wm + n * KM + k);
        *(us4*)&sW[n][k] = pk4(w);
    }
    {
        int el = t >> 3, sub = t & 7;
        int s = src[e0 + el];
        const float* np = node + (size_t)s * ND + sub * 16;
        #pragma unroll
        for (int i = 0; i < 4; ++i) {
            float4 v = *(const float4*)(np + i * 4);
            *(us4*)&sA[el][sub * 16 + i * 4] = pk4(v);
        }
        const float* ep = edgef + (size_t)(e0 + el) * ED + sub * 8;
        #pragma unroll
        for (int i = 0; i < 2; ++i) {
            float4 v = *(const float4*)(ep + i * 4);
            *(us4*)&sA[el][ND + sub * 8 + i * 4] = pk4(v);
        }
    }
    __syncthreads();

    const int w = t >> 6, lane = t & 63, l15 = lane & 15, lhi = lane >> 4;
    const int koff = lhi * 8;
    f32x4 acc[2][2] = {};

    #pragma unroll
    for (int ks = 0; ks < 6; ++ks) {
        bf16x8 a0 = *(const bf16x8*)&sA[l15][ks * 32 + koff];
        bf16x8 a1 = *(const bf16x8*)&sA[16 + l15][ks * 32 + koff];
        bf16x8 b0 = *(const bf16x8*)&sW[w * 32 + l15][ks * 32 + koff];
        bf16x8 b1 = *(const bf16x8*)&sW[w * 32 + 16 + l15][ks * 32 + koff];
        acc[0][0] = __builtin_amdgcn_mfma_f32_16x16x32_bf16(a0, b0, acc[0][0], 0, 0, 0);
        acc[1][0] = __builtin_amdgcn_mfma_f32_16x16x32_bf16(a1, b0, acc[1][0], 0, 0, 0);
        acc[0][1] = __builtin_amdgcn_mfma_f32_16x16x32_bf16(a0, b1, acc[0][1], 0, 0, 0);
        acc[1][1] = __builtin_amdgcn_mfma_f32_16x16x32_bf16(a1, b1, acc[1][1], 0, 0, 0);
    }

    #pragma unroll
    for (int ai = 0; ai < 2; ++ai) {
        #pragma unroll
        for (int r = 0; r < 4; ++r) {
            int el = ai * 16 + 4 * lhi + r;
            unsigned short* mrow = msg + (size_t)(e0 + el) * OD;
            #pragma unroll
            for (int bj = 0; bj < 2; ++bj) {
                int n = w * 32 + bj * 16 + l15;
                float v = acc[ai][bj][r] + bm[n];
                v = v > 0.f ? v : 0.f;
                mrow[n] = f2bf(v);
            }
        }
    }
}

// ---------------- aggregate: one wave per node, no atomics ----------------
__global__ __launch_bounds__(256) void agg_kernel(
    const unsigned short* __restrict__ msg, const int* __restrict__ off,
    const int* __restrict__ eid, float* __restrict__ hn)
{
    const int lane = threadIdx.x & 63;
    const int n = blockIdx.x * 4 + (threadIdx.x >> 6);
    if (n >= NN) return;
    const int d0 = off[n], d1 = off[n + 1];
    float a0 = 0.f, a1 = 0.f;
    for (int j = d0; j < d1; ++j) {
        int e = eid[j];
        uint32_t p = *(const uint32_t*)(msg + (size_t)e * OD + lane * 2);
        a0 += bfl(p);
        a1 += bfh(p);
    }
    float2* o = (float2*)(hn + (size_t)n * OD + lane * 2);
    *o = make_float2(a0, a1);
}

// ---------------- fallback atomic msg (ws too small) ----------------
__global__ __launch_bounds__(256, 2) void msg_kernel_atomic(
    const float* __restrict__ node, const float* __restrict__ edgef,
    const int* __restrict__ src, const int* __restrict__ dst,
    const float* __restrict__ Wm, const float* __restrict__ bm,
    float* __restrict__ hn)
{
    __shared__ unsigned short sW[OD][LK];
    __shared__ unsigned short sA[MT][LK];

    const int t  = threadIdx.x;
    const int e0 = blockIdx.x * MT;

    for (int i = t; i < OD * KM / 4; i += 256) {
        int base = i * 4;
        int n = base / KM, k = base % KM;
        float4 w = *(const float4*)(Wm + n * KM + k);
        *(us4*)&sW[n][k] = pk4(w);
    }
    {
        int el = t >> 3, sub = t & 7;
        int s = src[e0 + el];
        const float* np = node + (size_t)s * ND + sub * 16;
        #pragma unroll
        for (int i = 0; i < 4; ++i) {
            float4 v = *(const float4*)(np + i * 4);
            *(us4*)&sA[el][sub * 16 + i * 4] = pk4(v);
        }
        const float* ep = edgef + (size_t)(e0 + el) * ED + sub * 8;
        #pragma unroll
        for (int i = 0; i < 2; ++i) {
            float4 v = *(const float4*)(ep + i * 4);
            *(us4*)&sA[el][ND + sub * 8 + i * 4] = pk4(v);
        }
    }
    __syncthreads();

    const int w = t >> 6, lane = t & 63, l15 = lane & 15, lhi = lane >> 4;
    const int koff = lhi * 8;
    f32x4 acc[2][2] = {};

    #pragma unroll
    for (int ks = 0; ks < 6; ++ks) {
        bf16x8 a0 = *(const bf16x8*)&sA[l15][ks * 32 + koff];
        bf16x8 a1 = *(const bf16x8*)&sA[16 + l15][ks * 32 + koff];
        bf16x8 b0 = *(const bf16x8*)&sW[w * 32 + l15][ks * 32 + koff];
        bf16x8 b1 = *(const bf16x8*)&sW[w * 32 + 16 + l15][ks * 32 + koff];
        acc[0][0] = __builtin_amdgcn_mfma_f32_16x16x32_bf16(a0, b0, acc[0][0], 0, 0, 0);
        acc[1][0] = __builtin_amdgcn_mfma_f32_16x16x32_bf16(a1, b0, acc[1][0], 0, 0, 0);
        acc[0][1] = __builtin_amdgcn_mfma_f32_16x16x32_bf16(a0, b1, acc[0][1], 0, 0, 0);
        acc[1][1] = __builtin_amdgcn_mfma_f32_16x16x32_bf16(a1, b1, acc[1][1], 0, 0, 0);
    }

    #pragma unroll
    for (int ai = 0; ai < 2; ++ai) {
        #pragma unroll
        for (int r = 0; r < 4; ++r) {
            int el = ai * 16 + 4 * lhi + r;
            int d  = dst[e0 + el];
            float* hrow = hn + (size_t)d * OD;
            #pragma unroll
            for (int bj = 0; bj < 2; ++bj) {
                int n = w * 32 + bj * 16 + l15;
                float v = acc[ai][bj][r] + bm[n];
                v = v > 0.f ? v : 0.f;
                atomicAdd(hrow + n, v);
            }
        }
    }
}

// ---------------- apply: relu([node | h_neigh] @ Wa^T + ba) ----------------
#define AT 32
#define LKA (KA + 8)
#define LKW (128 + 8)

__global__ __launch_bounds__(256, 2) void apply_kernel(
    const float* __restrict__ node, const float* __restrict__ hn,
    const float* __restrict__ Wa, const float* __restrict__ ba,
    float* __restrict__ out)
{
    __shared__ unsigned short sW[OD][LKW];
    __shared__ unsigned short sA[AT][LKA];

    const int t  = threadIdx.x;
    const int n0 = blockIdx.x * AT;

    {
        int el = t >> 3, sub = t & 7;
        const float* np = node + (size_t)(n0 + el) * ND + sub * 16;
        #pragma unroll
        for (int i = 0; i < 4; ++i) {
            float4 v = *(const float4*)(np + i * 4);
            *(us4*)&sA[el][sub * 16 + i * 4] = pk4(v);
        }
        const float* hp = hn + (size_t)(n0 + el) * OD + sub * 16;
        #pragma unroll
        for (int i = 0; i < 4; ++i) {
            float4 v = *(const float4*)(hp + i * 4);
            *(us4*)&sA[el][ND + sub * 16 + i * 4] = pk4(v);
        }
    }
    for (int i = t; i < OD * 128 / 4; i += 256) {
        int base = i * 4;
        int n = base / 128, k = base % 128;
        float4 w = *(const float4*)(Wa + n * KA + k);
        *(us4*)&sW[n][k] = pk4(w);
    }
    __syncthreads();

    const int w = t >> 6, lane = t & 63, l15 = lane & 15, lhi = lane >> 4;
    const int koff = lhi * 8;
    f32x4 acc[2][2] = {};

    #pragma unroll
    for (int ks = 0; ks < 4; ++ks) {
        bf16x8 a0 = *(const bf16x8*)&sA[l15][ks * 32 + koff];
        bf16x8 a1 = *(const bf16x8*)&sA[16 + l15][ks * 32 + koff];
        bf16x8 b0 = *(const bf16x8*)&sW[w * 32 + l15][ks * 32 + koff];
        bf16x8 b1 = *(const bf16x8*)&sW[w * 32 + 16 + l15][ks * 32 + koff];
        acc[0][0] = __builtin_amdgcn_mfma_f32_16x16x32_bf16(a0, b0, acc[0][0], 0, 0, 0);
        acc[1][0] = __builtin_amdgcn_mfma_f32_16x16x32_bf16(a1, b0, acc[1][0], 0, 0, 0);
        acc[0][1] = __builtin_amdgcn_mfma_f32_16x16x32_bf16(a0, b1, acc[0][1], 0, 0, 0);
        acc[1][1] = __builtin_amdgcn_mfma_f32_16x16x32_bf16(a1, b1, acc[1][1], 0, 0, 0);
    }
    __syncthreads();
    for (int i = t; i < OD * 128 / 4; i += 256) {
        int base = i * 4;
        int n = base / 128, k = base % 128;
        float4 w = *(const float4*)(Wa + n * KA + 128 + k);
        *(us4*)&sW[n][k] = pk4(w);
    }
    __syncthreads();
    #pragma unroll
    for (int ks = 0; ks < 4; ++ks) {
        bf16x8 a0 = *(const bf16x8*)&sA[l15][128 + ks * 32 + koff];
        bf16x8 a1 = *(const bf16x8*)&sA[16 + l15][128 + ks * 32 + koff];
        bf16x8 b0 = *(const bf16x8*)&sW[w * 32 + l15][ks * 32 + koff];
        bf16x8 b1 = *(const bf16x8*)&sW[w * 32 + 16 + l15][ks * 32 + koff];
        acc[0][0] = __builtin_amdgcn_mfma_f32_16x16x32_bf16(a0, b0, acc[0][0], 0, 0, 0);
        acc[1][0] = __builtin_amdgcn_mfma_f32_16x16x32_bf16(a1, b0, acc[1][0], 0, 0, 0);
        acc[0][1] = __builtin_amdgcn_mfma_f32_16x16x32_bf16(a0, b1, acc[0][1], 0, 0, 0);
        acc[1][1] = __builtin_amdgcn_mfma_f32_16x16x32_bf16(a1, b1, acc[1][1], 0, 0, 0);
    }

    #pragma unroll
    for (int ai = 0; ai < 2; ++ai) {
        #pragma unroll
        for (int r = 0; r < 4; ++r) {
            int nd = n0 + ai * 16 + 4 * lhi + r;
            #pragma unroll
            for (int bj = 0; bj < 2; ++bj) {
                int n = w * 32 + bj * 16 + l15;
                float v = acc[ai][bj][r] + ba[n];
                out[(size_t)nd * OD + n] = v > 0.f ? v : 0.f;
            }
        }
    }
}

extern "C" void kernel_launch(void* const* d_in, const int* in_sizes, int n_in,
                              void* d_out, int out_size, void* d_ws, size_t ws_size,
                              hipStream_t stream) {
    const float* node  = (const float*)d_in[0];
    const float* edgef = (const float*)d_in[1];
    const int*   src   = (const int*)d_in[2];
    const int*   dst   = (const int*)d_in[3];
    const float* Wm    = (const float*)d_in[4];
    const float* bm    = (const float*)d_in[5];
    const float* Wa    = (const float*)d_in[6];
    const float* ba    = (const float*)d_in[7];
    float* out = (float*)d_out;

    // ws layout
    const size_t o_msg = 0;
    const size_t sz_msg = (size_t)NE * OD * 2;          // 163,840,000
    const size_t o_hn  = o_msg + sz_msg;
    const size_t sz_hn = (size_t)NN * OD * 4;           // 20,480,000
    const size_t o_eid = o_hn + sz_hn;
    const size_t sz_eid = (size_t)NE * 4;               // 2,560,000
    const size_t o_off = o_eid + sz_eid;
    const size_t sz_off = (size_t)(NN + 1) * 4;
    const size_t o_cur = o_off + ((sz_off + 15) & ~(size_t)15);
    const size_t sz_cur = (size_t)NN * 4;
    const size_t need = o_cur + sz_cur;                 // ~187.2 MB

    char* ws = (char*)d_ws;

    if (ws_size >= need) {
        unsigned short* msg = (unsigned short*)(ws + o_msg);
        float* hn = (float*)(ws + o_hn);
        int* eid  = (int*)(ws + o_eid);
        int* off  = (int*)(ws + o_off);
        int* cur  = (int*)(ws + o_cur);

        hipMemsetAsync(cur, 0, sz_cur, stream);
        hist_kernel<<<(NE + 255) / 256, 256, 0, stream>>>(dst, cur);
        scan_kernel<<<1, 1024, 0, stream>>>(cur, off);
        scatter_kernel<<<(NE + 255) / 256, 256, 0, stream>>>(dst, cur, eid);
        msg_kernel<<<NE / MT, 256, 0, stream>>>(node, edgef, src, Wm, bm, msg);
        agg_kernel<<<(NN + 3) / 4, 256, 0, stream>>>(msg, off, eid, hn);
        apply_kernel<<<NN / AT, 256, 0, stream>>>(node, hn, Wa, ba, out);
    } else {
        const size_t hn_bytes = (size_t)NN * OD * 4;
        float* hn = (ws_size >= hn_bytes) ? (float*)d_ws : out;
        hipMemsetAsync(hn, 0, hn_bytes, stream);
        msg_kernel_atomic<<<NE / MT, 256, 0, stream>>>(node, edgef, src, dst, Wm, bm, hn);
        apply_kernel<<<NN / AT, 256, 0, stream>>>(node, hn, Wa, ba, out);
    }
}

// Round 3
// 343.497 us; speedup vs baseline: 1.5633x; 1.5633x over previous
//
#include <hip/hip_runtime.h>
#include <stdint.h>

#define NN 40000
#define NE 640000
#define ND 128
#define ED 64
#define OD 128
#define KM 192   // ND + ED
#define KA 256   // ND + OD

typedef __attribute__((ext_vector_type(8))) short bf16x8;
typedef __attribute__((ext_vector_type(4))) float f32x4;
typedef __attribute__((ext_vector_type(4))) unsigned short us4;

__device__ __forceinline__ unsigned short f2bf(float f) {
    union { float f; uint32_t u; } v; v.f = f;
    return (unsigned short)((v.u + 0x7fffu + ((v.u >> 16) & 1u)) >> 16);
}
__device__ __forceinline__ us4 pk4(float4 v) {
    us4 r; r.x = f2bf(v.x); r.y = f2bf(v.y); r.z = f2bf(v.z); r.w = f2bf(v.w);
    return r;
}
__device__ __forceinline__ bf16x8 pk8(float4 a, float4 b) {
    bf16x8 r;
    r[0] = (short)f2bf(a.x); r[1] = (short)f2bf(a.y);
    r[2] = (short)f2bf(a.z); r[3] = (short)f2bf(a.w);
    r[4] = (short)f2bf(b.x); r[5] = (short)f2bf(b.y);
    r[6] = (short)f2bf(b.z); r[7] = (short)f2bf(b.w);
    return r;
}
__device__ __forceinline__ float bfl(uint32_t u) {
    union { uint32_t u; float f; } v; v.u = u << 16; return v.f;
}
__device__ __forceinline__ float bfh(uint32_t u) {
    union { uint32_t u; float f; } v; v.u = u & 0xffff0000u; return v.f;
}

// ---------------- CSR build ----------------
__global__ void hist_kernel(const int* __restrict__ dst, int* __restrict__ cnt) {
    int e = blockIdx.x * blockDim.x + threadIdx.x;
    if (e < NE) atomicAdd(&cnt[dst[e]], 1);
}

__global__ __launch_bounds__(1024) void scan_kernel(
    int* __restrict__ cnt_cur, int* __restrict__ off)
{
    __shared__ int wsum[16];
    __shared__ int carry_s;
    const int t = threadIdx.x;
    if (t == 0) carry_s = 0;
    __syncthreads();
    for (int base = 0; base < NN; base += 1024) {
        int idx = base + t;
        int v = (idx < NN) ? cnt_cur[idx] : 0;
        int x = v;
        #pragma unroll
        for (int d = 1; d < 64; d <<= 1) {
            int y = __shfl_up(x, d, 64);
            if ((t & 63) >= d) x += y;
        }
        int wid = t >> 6;
        if ((t & 63) == 63) wsum[wid] = x;
        __syncthreads();
        if (t < 16) {
            int s = wsum[t];
            #pragma unroll
            for (int d = 1; d < 16; d <<= 1) {
                int y = __shfl_up(s, d, 64);
                if (t >= d) s += y;
            }
            wsum[t] = s;
        }
        __syncthreads();
        int wave_prefix = (wid > 0) ? wsum[wid - 1] : 0;
        int incl = x + wave_prefix + carry_s;
        int excl = incl - v;
        if (idx < NN) { off[idx] = excl; cnt_cur[idx] = excl; }
        __syncthreads();
        if (t == 1023) carry_s = incl;
        __syncthreads();
    }
    if (t == 0) off[NN] = carry_s;
}

__global__ void scatter_kernel(const int* __restrict__ dst, const int* __restrict__ src,
                               int* __restrict__ cur, int* __restrict__ eid,
                               int* __restrict__ srcp) {
    int e = blockIdx.x * blockDim.x + threadIdx.x;
    if (e < NE) {
        int p = atomicAdd(&cur[dst[e]], 1);
        eid[p]  = e;
        srcp[p] = src[e];
    }
}

// ---------------- proj: P = node @ Wn^T (bf16 out, no bias) ----------------
#define PT 32
__global__ __launch_bounds__(256, 2) void proj_kernel(
    const float* __restrict__ node, const float* __restrict__ Wm,
    unsigned short* __restrict__ P)
{
    __shared__ unsigned short sW[OD][136];
    __shared__ unsigned short sA[PT][136];
    const int t = threadIdx.x, n0 = blockIdx.x * PT;
    {
        int el = t >> 3, sub = t & 7;
        const float* np = node + (size_t)(n0 + el) * ND + sub * 16;
        #pragma unroll
        for (int i = 0; i < 4; ++i) {
            float4 v = *(const float4*)(np + i * 4);
            *(us4*)&sA[el][sub * 16 + i * 4] = pk4(v);
        }
    }
    for (int i = t; i < OD * 128 / 4; i += 256) {
        int base = i * 4;
        int n = base / 128, k = base % 128;
        float4 wv = *(const float4*)(Wm + n * KM + k);  // Wn = cols [0,128)
        *(us4*)&sW[n][k] = pk4(wv);
    }
    __syncthreads();

    const int w = t >> 6, lane = t & 63, l15 = lane & 15, lhi = lane >> 4;
    const int koff = lhi * 8;
    f32x4 acc[2][2] = {};
    #pragma unroll
    for (int ks = 0; ks < 4; ++ks) {
        bf16x8 a0 = *(const bf16x8*)&sA[l15][ks * 32 + koff];
        bf16x8 a1 = *(const bf16x8*)&sA[16 + l15][ks * 32 + koff];
        bf16x8 b0 = *(const bf16x8*)&sW[w * 32 + l15][ks * 32 + koff];
        bf16x8 b1 = *(const bf16x8*)&sW[w * 32 + 16 + l15][ks * 32 + koff];
        acc[0][0] = __builtin_amdgcn_mfma_f32_16x16x32_bf16(a0, b0, acc[0][0], 0, 0, 0);
        acc[1][0] = __builtin_amdgcn_mfma_f32_16x16x32_bf16(a1, b0, acc[1][0], 0, 0, 0);
        acc[0][1] = __builtin_amdgcn_mfma_f32_16x16x32_bf16(a0, b1, acc[0][1], 0, 0, 0);
        acc[1][1] = __builtin_amdgcn_mfma_f32_16x16x32_bf16(a1, b1, acc[1][1], 0, 0, 0);
    }
    #pragma unroll
    for (int ai = 0; ai < 2; ++ai)
        #pragma unroll
        for (int r = 0; r < 4; ++r) {
            int m = n0 + ai * 16 + 4 * lhi + r;
            #pragma unroll
            for (int bj = 0; bj < 2; ++bj) {
                int n = w * 32 + bj * 16 + l15;
                P[(size_t)m * OD + n] = f2bf(acc[ai][bj][r]);
            }
        }
}

// ---------------- msgp: dst-sorted messages, W-in-registers ----------------
// msgp[j] = relu(P[srcp[j]] + edgef[eid[j]] @ We^T + bm)   (bf16 out)
#define QT 64
__global__ __launch_bounds__(256, 4) void msgp_kernel(
    const float* __restrict__ edgef, const int* __restrict__ eid,
    const int* __restrict__ srcp, const unsigned short* __restrict__ P,
    const float* __restrict__ Wm, const float* __restrict__ bm,
    unsigned short* __restrict__ msgp)
{
    __shared__ unsigned short sE[QT][72];    // edge feats bf16
    __shared__ unsigned short sP[QT][136];   // gathered P rows bf16

    const int t = threadIdx.x, j0 = blockIdx.x * QT;
    const int w = t >> 6, lane = t & 63, l15 = lane & 15, lhi = lane >> 4;

    // B fragments in registers: We = Wm[:, 128:192)
    bf16x8 bw[2][2];  // [ks][bj]
    #pragma unroll
    for (int bj = 0; bj < 2; ++bj) {
        int n = w * 32 + bj * 16 + l15;
        const float* wp = Wm + n * KM + ND;
        #pragma unroll
        for (int ks = 0; ks < 2; ++ks) {
            float4 x = *(const float4*)(wp + ks * 32 + lhi * 8);
            float4 y = *(const float4*)(wp + ks * 32 + lhi * 8 + 4);
            bw[ks][bj] = pk8(x, y);
        }
    }
    float bmv[2] = { bm[w * 32 + l15], bm[w * 32 + 16 + l15] };

    // stage: 4 threads per row (edge)
    {
        int row = t >> 2, s4 = t & 3;
        int e  = eid[j0 + row];
        int sp = srcp[j0 + row];
        const float* ep = edgef + (size_t)e * ED + s4 * 16;
        #pragma unroll
        for (int i = 0; i < 4; ++i) {
            float4 v = *(const float4*)(ep + i * 4);
            *(us4*)&sE[row][s4 * 16 + i * 4] = pk4(v);
        }
        const uint4* pp = (const uint4*)(P + (size_t)sp * OD) + s4 * 4;
        #pragma unroll
        for (int i = 0; i < 4; ++i) {
            *(uint4*)&sP[row][s4 * 32 + i * 8] = pp[i];
        }
    }
    __syncthreads();

    f32x4 acc[4][2] = {};
    #pragma unroll
    for (int ks = 0; ks < 2; ++ks) {
        bf16x8 a[4];
        #pragma unroll
        for (int ai = 0; ai < 4; ++ai)
            a[ai] = *(const bf16x8*)&sE[ai * 16 + l15][ks * 32 + lhi * 8];
        #pragma unroll
        for (int ai = 0; ai < 4; ++ai) {
            acc[ai][0] = __builtin_amdgcn_mfma_f32_16x16x32_bf16(a[ai], bw[ks][0], acc[ai][0], 0, 0, 0);
            acc[ai][1] = __builtin_amdgcn_mfma_f32_16x16x32_bf16(a[ai], bw[ks][1], acc[ai][1], 0, 0, 0);
        }
    }

    #pragma unroll
    for (int ai = 0; ai < 4; ++ai)
        #pragma unroll
        for (int r = 0; r < 4; ++r) {
            int m = ai * 16 + 4 * lhi + r;
            unsigned short* orow = msgp + (size_t)(j0 + m) * OD;
            #pragma unroll
            for (int bj = 0; bj < 2; ++bj) {
                int n = w * 32 + bj * 16 + l15;
                float v = acc[ai][bj][r] + bmv[bj] + bfl(sP[m][n]);
                v = v > 0.f ? v : 0.f;
                orow[n] = f2bf(v);
            }
        }
}

// ---------------- aggregate: sequential segmented sum ----------------
__global__ __launch_bounds__(256) void agg_kernel(
    const unsigned short* __restrict__ msgp, const int* __restrict__ off,
    float* __restrict__ hn)
{
    const int lane = threadIdx.x & 63;
    const int n = blockIdx.x * 4 + (threadIdx.x >> 6);
    if (n >= NN) return;
    const int d0 = off[n], d1 = off[n + 1];
    float a0 = 0.f, a1 = 0.f;
    const uint32_t* p = (const uint32_t*)msgp + (size_t)d0 * 64 + lane;
    for (int j = d0; j < d1; ++j) {
        uint32_t v = *p; p += 64;
        a0 += bfl(v);
        a1 += bfh(v);
    }
    ((float2*)(hn + (size_t)n * OD))[lane] = make_float2(a0, a1);
}

// ---------------- fallback atomic msg (ws too small) ----------------
#define MT 32
#define LK (KM + 8)
__global__ __launch_bounds__(256, 2) void msg_kernel_atomic(
    const float* __restrict__ node, const float* __restrict__ edgef,
    const int* __restrict__ src, const int* __restrict__ dst,
    const float* __restrict__ Wm, const float* __restrict__ bm,
    float* __restrict__ hn)
{
    __shared__ unsigned short sW[OD][LK];
    __shared__ unsigned short sA[MT][LK];

    const int t  = threadIdx.x;
    const int e0 = blockIdx.x * MT;

    for (int i = t; i < OD * KM / 4; i += 256) {
        int base = i * 4;
        int n = base / KM, k = base % KM;
        float4 w = *(const float4*)(Wm + n * KM + k);
        *(us4*)&sW[n][k] = pk4(w);
    }
    {
        int el = t >> 3, sub = t & 7;
        int s = src[e0 + el];
        const float* np = node + (size_t)s * ND + sub * 16;
        #pragma unroll
        for (int i = 0; i < 4; ++i) {
            float4 v = *(const float4*)(np + i * 4);
            *(us4*)&sA[el][sub * 16 + i * 4] = pk4(v);
        }
        const float* ep = edgef + (size_t)(e0 + el) * ED + sub * 8;
        #pragma unroll
        for (int i = 0; i < 2; ++i) {
            float4 v = *(const float4*)(ep + i * 4);
            *(us4*)&sA[el][ND + sub * 8 + i * 4] = pk4(v);
        }
    }
    __syncthreads();

    const int w = t >> 6, lane = t & 63, l15 = lane & 15, lhi = lane >> 4;
    const int koff = lhi * 8;
    f32x4 acc[2][2] = {};

    #pragma unroll
    for (int ks = 0; ks < 6; ++ks) {
        bf16x8 a0 = *(const bf16x8*)&sA[l15][ks * 32 + koff];
        bf16x8 a1 = *(const bf16x8*)&sA[16 + l15][ks * 32 + koff];
        bf16x8 b0 = *(const bf16x8*)&sW[w * 32 + l15][ks * 32 + koff];
        bf16x8 b1 = *(const bf16x8*)&sW[w * 32 + 16 + l15][ks * 32 + koff];
        acc[0][0] = __builtin_amdgcn_mfma_f32_16x16x32_bf16(a0, b0, acc[0][0], 0, 0, 0);
        acc[1][0] = __builtin_amdgcn_mfma_f32_16x16x32_bf16(a1, b0, acc[1][0], 0, 0, 0);
        acc[0][1] = __builtin_amdgcn_mfma_f32_16x16x32_bf16(a0, b1, acc[0][1], 0, 0, 0);
        acc[1][1] = __builtin_amdgcn_mfma_f32_16x16x32_bf16(a1, b1, acc[1][1], 0, 0, 0);
    }

    #pragma unroll
    for (int ai = 0; ai < 2; ++ai)
        #pragma unroll
        for (int r = 0; r < 4; ++r) {
            int el = ai * 16 + 4 * lhi + r;
            int d  = dst[e0 + el];
            float* hrow = hn + (size_t)d * OD;
            #pragma unroll
            for (int bj = 0; bj < 2; ++bj) {
                int n = w * 32 + bj * 16 + l15;
                float v = acc[ai][bj][r] + bm[n];
                v = v > 0.f ? v : 0.f;
                atomicAdd(hrow + n, v);
            }
        }
}

// ---------------- apply: relu([node | h_neigh] @ Wa^T + ba) ----------------
#define AT 32
#define LKA (KA + 8)
#define LKW (128 + 8)

__global__ __launch_bounds__(256, 2) void apply_kernel(
    const float* __restrict__ node, const float* __restrict__ hn,
    const float* __restrict__ Wa, const float* __restrict__ ba,
    float* __restrict__ out)
{
    __shared__ unsigned short sW[OD][LKW];
    __shared__ unsigned short sA[AT][LKA];

    const int t  = threadIdx.x;
    const int n0 = blockIdx.x * AT;

    {
        int el = t >> 3, sub = t & 7;
        const float* np = node + (size_t)(n0 + el) * ND + sub * 16;
        #pragma unroll
        for (int i = 0; i < 4; ++i) {
            float4 v = *(const float4*)(np + i * 4);
            *(us4*)&sA[el][sub * 16 + i * 4] = pk4(v);
        }
        const float* hp = hn + (size_t)(n0 + el) * OD + sub * 16;
        #pragma unroll
        for (int i = 0; i < 4; ++i) {
            float4 v = *(const float4*)(hp + i * 4);
            *(us4*)&sA[el][ND + sub * 16 + i * 4] = pk4(v);
        }
    }
    for (int i = t; i < OD * 128 / 4; i += 256) {
        int base = i * 4;
        int n = base / 128, k = base % 128;
        float4 w = *(const float4*)(Wa + n * KA + k);
        *(us4*)&sW[n][k] = pk4(w);
    }
    __syncthreads();

    const int w = t >> 6, lane = t & 63, l15 = lane & 15, lhi = lane >> 4;
    const int koff = lhi * 8;
    f32x4 acc[2][2] = {};

    #pragma unroll
    for (int ks = 0; ks < 4; ++ks) {
        bf16x8 a0 = *(const bf16x8*)&sA[l15][ks * 32 + koff];
        bf16x8 a1 = *(const bf16x8*)&sA[16 + l15][ks * 32 + koff];
        bf16x8 b0 = *(const bf16x8*)&sW[w * 32 + l15][ks * 32 + koff];
        bf16x8 b1 = *(const bf16x8*)&sW[w * 32 + 16 + l15][ks * 32 + koff];
        acc[0][0] = __builtin_amdgcn_mfma_f32_16x16x32_bf16(a0, b0, acc[0][0], 0, 0, 0);
        acc[1][0] = __builtin_amdgcn_mfma_f32_16x16x32_bf16(a1, b0, acc[1][0], 0, 0, 0);
        acc[0][1] = __builtin_amdgcn_mfma_f32_16x16x32_bf16(a0, b1, acc[0][1], 0, 0, 0);
        acc[1][1] = __builtin_amdgcn_mfma_f32_16x16x32_bf16(a1, b1, acc[1][1], 0, 0, 0);
    }
    __syncthreads();
    for (int i = t; i < OD * 128 / 4; i += 256) {
        int base = i * 4;
        int n = base / 128, k = base % 128;
        float4 w = *(const float4*)(Wa + n * KA + 128 + k);
        *(us4*)&sW[n][k] = pk4(w);
    }
    __syncthreads();
    #pragma unroll
    for (int ks = 0; ks < 4; ++ks) {
        bf16x8 a0 = *(const bf16x8*)&sA[l15][128 + ks * 32 + koff];
        bf16x8 a1 = *(const bf16x8*)&sA[16 + l15][128 + ks * 32 + koff];
        bf16x8 b0 = *(const bf16x8*)&sW[w * 32 + l15][ks * 32 + koff];
        bf16x8 b1 = *(const bf16x8*)&sW[w * 32 + 16 + l15][ks * 32 + koff];
        acc[0][0] = __builtin_amdgcn_mfma_f32_16x16x32_bf16(a0, b0, acc[0][0], 0, 0, 0);
        acc[1][0] = __builtin_amdgcn_mfma_f32_16x16x32_bf16(a1, b0, acc[1][0], 0, 0, 0);
        acc[0][1] = __builtin_amdgcn_mfma_f32_16x16x32_bf16(a0, b1, acc[0][1], 0, 0, 0);
        acc[1][1] = __builtin_amdgcn_mfma_f32_16x16x32_bf16(a1, b1, acc[1][1], 0, 0, 0);
    }

    #pragma unroll
    for (int ai = 0; ai < 2; ++ai)
        #pragma unroll
        for (int r = 0; r < 4; ++r) {
            int nd = n0 + ai * 16 + 4 * lhi + r;
            #pragma unroll
            for (int bj = 0; bj < 2; ++bj) {
                int n = w * 32 + bj * 16 + l15;
                float v = acc[ai][bj][r] + ba[n];
                out[(size_t)nd * OD + n] = v > 0.f ? v : 0.f;
            }
        }
}

extern "C" void kernel_launch(void* const* d_in, const int* in_sizes, int n_in,
                              void* d_out, int out_size, void* d_ws, size_t ws_size,
                              hipStream_t stream) {
    const float* node  = (const float*)d_in[0];
    const float* edgef = (const float*)d_in[1];
    const int*   src   = (const int*)d_in[2];
    const int*   dst   = (const int*)d_in[3];
    const float* Wm    = (const float*)d_in[4];
    const float* bm    = (const float*)d_in[5];
    const float* Wa    = (const float*)d_in[6];
    const float* ba    = (const float*)d_in[7];
    float* out = (float*)d_out;

    // ws layout
    const size_t o_msg  = 0;
    const size_t sz_msg = (size_t)NE * OD * 2;                   // 163.84 MB
    const size_t o_P    = o_msg + sz_msg;
    const size_t sz_P   = (size_t)NN * OD * 2;                   // 10.24 MB
    const size_t o_eid  = o_P + sz_P;
    const size_t sz_eid = (size_t)NE * 4;
    const size_t o_srcp = o_eid + sz_eid;
    const size_t sz_srcp= (size_t)NE * 4;
    const size_t o_off  = o_srcp + sz_srcp;
    const size_t sz_off = (size_t)(NN + 1) * 4;
    const size_t o_cur  = o_off + ((sz_off + 15) & ~(size_t)15);
    const size_t sz_cur = (size_t)NN * 4;
    const size_t need   = o_cur + sz_cur;                        // ~179.5 MB

    char* ws = (char*)d_ws;

    if (ws_size >= need) {
        unsigned short* msgp = (unsigned short*)(ws + o_msg);
        unsigned short* P    = (unsigned short*)(ws + o_P);
        int* eid  = (int*)(ws + o_eid);
        int* srcp = (int*)(ws + o_srcp);
        int* off  = (int*)(ws + o_off);
        int* cur  = (int*)(ws + o_cur);
        float* hn = out;   // aliasing is safe: agg fully overwrites, apply
                           // reads exactly the rows it later writes

        hipMemsetAsync(cur, 0, sz_cur, stream);
        hist_kernel<<<(NE + 255) / 256, 256, 0, stream>>>(dst, cur);
        scan_kernel<<<1, 1024, 0, stream>>>(cur, off);
        scatter_kernel<<<(NE + 255) / 256, 256, 0, stream>>>(dst, src, cur, eid, srcp);
        proj_kernel<<<NN / PT, 256, 0, stream>>>(node, Wm, P);
        msgp_kernel<<<NE / QT, 256, 0, stream>>>(edgef, eid, srcp, P, Wm, bm, msgp);
        agg_kernel<<<(NN + 3) / 4, 256, 0, stream>>>(msgp, off, hn);
        apply_kernel<<<NN / AT, 256, 0, stream>>>(node, hn, Wa, ba, out);
    } else {
        const size_t hn_bytes = (size_t)NN * OD * 4;
        float* hn = (ws_size >= hn_bytes) ? (float*)d_ws : out;
        hipMemsetAsync(hn, 0, hn_bytes, stream);
        msg_kernel_atomic<<<NE / MT, 256, 0, stream>>>(node, edgef, src, dst, Wm, bm, hn);
        apply_kernel<<<NN / AT, 256, 0, stream>>>(node, hn, Wa, ba, out);
    }
}

// Round 4
// 222.426 us; speedup vs baseline: 2.4142x; 1.5443x over previous
//
#include <hip/hip_runtime.h>
#include <stdint.h>

#define NN 40000
#define NE 640000
#define ND 128
#define ED 64
#define OD 128
#define KM 192   // ND + ED
#define KA 256   // ND + OD
#define NB 40    // scan blocks (40*1024 >= NN)

typedef __attribute__((ext_vector_type(8))) short bf16x8;
typedef __attribute__((ext_vector_type(4))) float f32x4;
typedef __attribute__((ext_vector_type(4))) unsigned short us4;

__device__ __forceinline__ unsigned short f2bf(float f) {
    union { float f; uint32_t u; } v; v.f = f;
    return (unsigned short)((v.u + 0x7fffu + ((v.u >> 16) & 1u)) >> 16);
}
__device__ __forceinline__ us4 pk4(float4 v) {
    us4 r; r.x = f2bf(v.x); r.y = f2bf(v.y); r.z = f2bf(v.z); r.w = f2bf(v.w);
    return r;
}
__device__ __forceinline__ bf16x8 pk8(float4 a, float4 b) {
    bf16x8 r;
    r[0] = (short)f2bf(a.x); r[1] = (short)f2bf(a.y);
    r[2] = (short)f2bf(a.z); r[3] = (short)f2bf(a.w);
    r[4] = (short)f2bf(b.x); r[5] = (short)f2bf(b.y);
    r[6] = (short)f2bf(b.z); r[7] = (short)f2bf(b.w);
    return r;
}
__device__ __forceinline__ float bfl(uint32_t u) {
    union { uint32_t u; float f; } v; v.u = u << 16; return v.f;
}

// ---------------- CSR build ----------------
__global__ void hist_kernel(const int* __restrict__ dst, int* __restrict__ cnt) {
    int e = blockIdx.x * blockDim.x + threadIdx.x;
    if (e < NE) atomicAdd(&cnt[dst[e]], 1);
}

// phase A: per-block exclusive scan of 1024 elems -> off[idx] (partial), bsum[b]
__global__ __launch_bounds__(1024) void scanA_kernel(
    const int* __restrict__ cnt, int* __restrict__ off, int* __restrict__ bsum)
{
    __shared__ int wsum[16];
    const int t = threadIdx.x, b = blockIdx.x;
    const int idx = b * 1024 + t;
    int v = (idx < NN) ? cnt[idx] : 0;
    int x = v;
    #pragma unroll
    for (int d = 1; d < 64; d <<= 1) {
        int y = __shfl_up(x, d, 64);
        if ((t & 63) >= d) x += y;
    }
    const int wid = t >> 6;
    if ((t & 63) == 63) wsum[wid] = x;
    __syncthreads();
    if (t < 16) {
        int s = wsum[t];
        #pragma unroll
        for (int d = 1; d < 16; d <<= 1) {
            int y = __shfl_up(s, d, 64);
            if (t >= d) s += y;
        }
        wsum[t] = s;
    }
    __syncthreads();
    int incl = x + (wid > 0 ? wsum[wid - 1] : 0);
    if (idx < NN) off[idx] = incl - v;
    if (t == 1023) bsum[b] = incl;
}

// phase B: scan the 40 block sums (single wave)
__global__ __launch_bounds__(64) void scanB_kernel(
    const int* __restrict__ bsum, int* __restrict__ boff, int* __restrict__ off)
{
    const int t = threadIdx.x;
    int v = (t < NB) ? bsum[t] : 0;
    int x = v;
    #pragma unroll
    for (int d = 1; d < 64; d <<= 1) {
        int y = __shfl_up(x, d, 64);
        if (t >= d) x += y;
    }
    if (t < NB) boff[t] = x - v;
    if (t == 63) off[NN] = x;
}

// phase C: add block offsets, init cursor
__global__ __launch_bounds__(1024) void scanC_kernel(
    int* __restrict__ off, const int* __restrict__ boff, int* __restrict__ cur)
{
    const int idx = blockIdx.x * 1024 + threadIdx.x;
    if (idx < NN) {
        int val = off[idx] + boff[blockIdx.x];
        off[idx] = val;
        cur[idx] = val;
    }
}

__global__ void scatter_kernel(const int* __restrict__ dst, const int* __restrict__ src,
                               int* __restrict__ cur, int* __restrict__ eid,
                               int* __restrict__ srcp, int* __restrict__ dstp) {
    int e = blockIdx.x * blockDim.x + threadIdx.x;
    if (e < NE) {
        int d = dst[e];
        int p = atomicAdd(&cur[d], 1);
        eid[p]  = e;
        srcp[p] = src[e];
        dstp[p] = d;
    }
}

// ---------------- proj: P = node @ Wn^T (bf16 out, no bias) ----------------
#define PT 32
__global__ __launch_bounds__(256, 2) void proj_kernel(
    const float* __restrict__ node, const float* __restrict__ Wm,
    unsigned short* __restrict__ P)
{
    __shared__ unsigned short sW[OD][136];
    __shared__ unsigned short sA[PT][136];
    const int t = threadIdx.x, n0 = blockIdx.x * PT;
    {
        int el = t >> 3, sub = t & 7;
        const float* np = node + (size_t)(n0 + el) * ND + sub * 16;
        #pragma unroll
        for (int i = 0; i < 4; ++i) {
            float4 v = *(const float4*)(np + i * 4);
            *(us4*)&sA[el][sub * 16 + i * 4] = pk4(v);
        }
    }
    for (int i = t; i < OD * 128 / 4; i += 256) {
        int base = i * 4;
        int n = base / 128, k = base % 128;
        float4 wv = *(const float4*)(Wm + n * KM + k);
        *(us4*)&sW[n][k] = pk4(wv);
    }
    __syncthreads();

    const int w = t >> 6, lane = t & 63, l15 = lane & 15, lhi = lane >> 4;
    const int koff = lhi * 8;
    f32x4 acc[2][2] = {};
    #pragma unroll
    for (int ks = 0; ks < 4; ++ks) {
        bf16x8 a0 = *(const bf16x8*)&sA[l15][ks * 32 + koff];
        bf16x8 a1 = *(const bf16x8*)&sA[16 + l15][ks * 32 + koff];
        bf16x8 b0 = *(const bf16x8*)&sW[w * 32 + l15][ks * 32 + koff];
        bf16x8 b1 = *(const bf16x8*)&sW[w * 32 + 16 + l15][ks * 32 + koff];
        acc[0][0] = __builtin_amdgcn_mfma_f32_16x16x32_bf16(a0, b0, acc[0][0], 0, 0, 0);
        acc[1][0] = __builtin_amdgcn_mfma_f32_16x16x32_bf16(a1, b0, acc[1][0], 0, 0, 0);
        acc[0][1] = __builtin_amdgcn_mfma_f32_16x16x32_bf16(a0, b1, acc[0][1], 0, 0, 0);
        acc[1][1] = __builtin_amdgcn_mfma_f32_16x16x32_bf16(a1, b1, acc[1][1], 0, 0, 0);
    }
    #pragma unroll
    for (int ai = 0; ai < 2; ++ai)
        #pragma unroll
        for (int r = 0; r < 4; ++r) {
            int m = n0 + ai * 16 + 4 * lhi + r;
            #pragma unroll
            for (int bj = 0; bj < 2; ++bj) {
                int n = w * 32 + bj * 16 + l15;
                P[(size_t)m * OD + n] = f2bf(acc[ai][bj][r]);
            }
        }
}

// ---------------- fused message + segmented aggregate ----------------
// Block: 64 dst-sorted edge slots. Messages computed in registers, dumped to
// LDS (aliased over staging buffers), then segmented-summed into hn.
// Interior segments: plain store. Boundary segments: atomicAdd.
#define QT 64
#define MROW 148   // u16 row stride for mbuf: 2*148 mod 32 banks => +8/group, conflict-free

__global__ __launch_bounds__(256, 4) void msgagg_kernel(
    const float* __restrict__ edgef, const int* __restrict__ eid,
    const int* __restrict__ srcp, const int* __restrict__ dstp,
    const unsigned short* __restrict__ P,
    const float* __restrict__ Wm, const float* __restrict__ bm,
    float* __restrict__ hn)
{
    __shared__ union {
        struct {
            unsigned short E[QT][72];    // 9216 B
            unsigned short Pp[QT][136];  // 17408 B
        } s;
        unsigned short m[QT][MROW];      // 18944 B <= 26624 B
    } u;
    __shared__ int sD[QT];

    const int t = threadIdx.x, j0 = blockIdx.x * QT;
    const int w = t >> 6, lane = t & 63, l15 = lane & 15, lhi = lane >> 4;

    // B fragments in registers: We = Wm[:, 128:192)
    bf16x8 bw[2][2];  // [ks][bj]
    #pragma unroll
    for (int bj = 0; bj < 2; ++bj) {
        int n = w * 32 + bj * 16 + l15;
        const float* wp = Wm + n * KM + ND;
        #pragma unroll
        for (int ks = 0; ks < 2; ++ks) {
            float4 x = *(const float4*)(wp + ks * 32 + lhi * 8);
            float4 y = *(const float4*)(wp + ks * 32 + lhi * 8 + 4);
            bw[ks][bj] = pk8(x, y);
        }
    }
    float bmv[2] = { bm[w * 32 + l15], bm[w * 32 + 16 + l15] };

    // stage: 4 threads per edge row
    {
        int row = t >> 2, s4 = t & 3;
        int e  = eid[j0 + row];
        int sp = srcp[j0 + row];
        const float* ep = edgef + (size_t)e * ED + s4 * 16;
        #pragma unroll
        for (int i = 0; i < 4; ++i) {
            float4 v = *(const float4*)(ep + i * 4);
            *(us4*)&u.s.E[row][s4 * 16 + i * 4] = pk4(v);
        }
        const uint4* pp = (const uint4*)(P + (size_t)sp * OD) + s4 * 4;
        #pragma unroll
        for (int i = 0; i < 4; ++i) {
            *(uint4*)&u.s.Pp[row][s4 * 32 + i * 8] = pp[i];
        }
    }
    if (t < QT) sD[t] = dstp[j0 + t];
    __syncthreads();

    f32x4 acc[4][2] = {};
    #pragma unroll
    for (int ks = 0; ks < 2; ++ks) {
        bf16x8 a[4];
        #pragma unroll
        for (int ai = 0; ai < 4; ++ai)
            a[ai] = *(const bf16x8*)&u.s.E[ai * 16 + l15][ks * 32 + lhi * 8];
        #pragma unroll
        for (int ai = 0; ai < 4; ++ai) {
            acc[ai][0] = __builtin_amdgcn_mfma_f32_16x16x32_bf16(a[ai], bw[ks][0], acc[ai][0], 0, 0, 0);
            acc[ai][1] = __builtin_amdgcn_mfma_f32_16x16x32_bf16(a[ai], bw[ks][1], acc[ai][1], 0, 0, 0);
        }
    }

    // epilogue into registers: relu(acc + bias + P)
    #pragma unroll
    for (int ai = 0; ai < 4; ++ai)
        #pragma unroll
        for (int r = 0; r < 4; ++r) {
            int m = ai * 16 + 4 * lhi + r;
            #pragma unroll
            for (int bj = 0; bj < 2; ++bj) {
                int n = w * 32 + bj * 16 + l15;
                float v = acc[ai][bj][r] + bmv[bj] + bfl(u.s.Pp[m][n]);
                acc[ai][bj][r] = v > 0.f ? v : 0.f;
            }
        }
    __syncthreads();   // all reads of E/Pp complete

    // dump message tile to LDS (aliased)
    #pragma unroll
    for (int ai = 0; ai < 4; ++ai)
        #pragma unroll
        for (int r = 0; r < 4; ++r) {
            int m = ai * 16 + 4 * lhi + r;
            #pragma unroll
            for (int bj = 0; bj < 2; ++bj) {
                int n = w * 32 + bj * 16 + l15;
                u.m[m][n] = f2bf(acc[ai][bj][r]);
            }
        }
    __syncthreads();

    // segmented sum: 128 threads, one column each; dst run is monotone
    if (t < OD) {
        const int c = t;
        int dprev = sD[0];
        int start = 0;
        float accv = bfl(u.m[0][c]);
        #pragma unroll 4
        for (int r = 1; r < QT; ++r) {
            int d = sD[r];                     // wave-uniform broadcast
            float v = bfl(u.m[r][c]);
            if (d != dprev) {
                float* dest = hn + (size_t)dprev * OD + c;
                if (start > 0) *dest = accv;   // interior: only this block touches it
                else atomicAdd(dest, accv);
                accv = v; dprev = d; start = r;
            } else {
                accv += v;
            }
        }
        atomicAdd(hn + (size_t)dprev * OD + c, accv);  // last segment: boundary
    }
}

// ---------------- fallback atomic msg (ws too small) ----------------
#define MT 32
#define LK (KM + 8)
__global__ __launch_bounds__(256, 2) void msg_kernel_atomic(
    const float* __restrict__ node, const float* __restrict__ edgef,
    const int* __restrict__ src, const int* __restrict__ dst,
    const float* __restrict__ Wm, const float* __restrict__ bm,
    float* __restrict__ hn)
{
    __shared__ unsigned short sW[OD][LK];
    __shared__ unsigned short sA[MT][LK];

    const int t  = threadIdx.x;
    const int e0 = blockIdx.x * MT;

    for (int i = t; i < OD * KM / 4; i += 256) {
        int base = i * 4;
        int n = base / KM, k = base % KM;
        float4 w = *(const float4*)(Wm + n * KM + k);
        *(us4*)&sW[n][k] = pk4(w);
    }
    {
        int el = t >> 3, sub = t & 7;
        int s = src[e0 + el];
        const float* np = node + (size_t)s * ND + sub * 16;
        #pragma unroll
        for (int i = 0; i < 4; ++i) {
            float4 v = *(const float4*)(np + i * 4);
            *(us4*)&sA[el][sub * 16 + i * 4] = pk4(v);
        }
        const float* ep = edgef + (size_t)(e0 + el) * ED + sub * 8;
        #pragma unroll
        for (int i = 0; i < 2; ++i) {
            float4 v = *(const float4*)(ep + i * 4);
            *(us4*)&sA[el][ND + sub * 8 + i * 4] = pk4(v);
        }
    }
    __syncthreads();

    const int w = t >> 6, lane = t & 63, l15 = lane & 15, lhi = lane >> 4;
    const int koff = lhi * 8;
    f32x4 acc[2][2] = {};

    #pragma unroll
    for (int ks = 0; ks < 6; ++ks) {
        bf16x8 a0 = *(const bf16x8*)&sA[l15][ks * 32 + koff];
        bf16x8 a1 = *(const bf16x8*)&sA[16 + l15][ks * 32 + koff];
        bf16x8 b0 = *(const bf16x8*)&sW[w * 32 + l15][ks * 32 + koff];
        bf16x8 b1 = *(const bf16x8*)&sW[w * 32 + 16 + l15][ks * 32 + koff];
        acc[0][0] = __builtin_amdgcn_mfma_f32_16x16x32_bf16(a0, b0, acc[0][0], 0, 0, 0);
        acc[1][0] = __builtin_amdgcn_mfma_f32_16x16x32_bf16(a1, b0, acc[1][0], 0, 0, 0);
        acc[0][1] = __builtin_amdgcn_mfma_f32_16x16x32_bf16(a0, b1, acc[0][1], 0, 0, 0);
        acc[1][1] = __builtin_amdgcn_mfma_f32_16x16x32_bf16(a1, b1, acc[1][1], 0, 0, 0);
    }

    #pragma unroll
    for (int ai = 0; ai < 2; ++ai)
        #pragma unroll
        for (int r = 0; r < 4; ++r) {
            int el = ai * 16 + 4 * lhi + r;
            int d  = dst[e0 + el];
            float* hrow = hn + (size_t)d * OD;
            #pragma unroll
            for (int bj = 0; bj < 2; ++bj) {
                int n = w * 32 + bj * 16 + l15;
                float v = acc[ai][bj][r] + bm[n];
                v = v > 0.f ? v : 0.f;
                atomicAdd(hrow + n, v);
            }
        }
}

// ---------------- apply: relu([node | h_neigh] @ Wa^T + ba) ----------------
#define AT 32
#define LKA (KA + 8)
#define LKW (128 + 8)

__global__ __launch_bounds__(256, 2) void apply_kernel(
    const float* __restrict__ node, const float* __restrict__ hn,
    const float* __restrict__ Wa, const float* __restrict__ ba,
    float* __restrict__ out)
{
    __shared__ unsigned short sW[OD][LKW];
    __shared__ unsigned short sA[AT][LKA];

    const int t  = threadIdx.x;
    const int n0 = blockIdx.x * AT;

    {
        int el = t >> 3, sub = t & 7;
        const float* np = node + (size_t)(n0 + el) * ND + sub * 16;
        #pragma unroll
        for (int i = 0; i < 4; ++i) {
            float4 v = *(const float4*)(np + i * 4);
            *(us4*)&sA[el][sub * 16 + i * 4] = pk4(v);
        }
        const float* hp = hn + (size_t)(n0 + el) * OD + sub * 16;
        #pragma unroll
        for (int i = 0; i < 4; ++i) {
            float4 v = *(const float4*)(hp + i * 4);
            *(us4*)&sA[el][ND + sub * 16 + i * 4] = pk4(v);
        }
    }
    for (int i = t; i < OD * 128 / 4; i += 256) {
        int base = i * 4;
        int n = base / 128, k = base % 128;
        float4 w = *(const float4*)(Wa + n * KA + k);
        *(us4*)&sW[n][k] = pk4(w);
    }
    __syncthreads();

    const int w = t >> 6, lane = t & 63, l15 = lane & 15, lhi = lane >> 4;
    const int koff = lhi * 8;
    f32x4 acc[2][2] = {};

    #pragma unroll
    for (int ks = 0; ks < 4; ++ks) {
        bf16x8 a0 = *(const bf16x8*)&sA[l15][ks * 32 + koff];
        bf16x8 a1 = *(const bf16x8*)&sA[16 + l15][ks * 32 + koff];
        bf16x8 b0 = *(const bf16x8*)&sW[w * 32 + l15][ks * 32 + koff];
        bf16x8 b1 = *(const bf16x8*)&sW[w * 32 + 16 + l15][ks * 32 + koff];
        acc[0][0] = __builtin_amdgcn_mfma_f32_16x16x32_bf16(a0, b0, acc[0][0], 0, 0, 0);
        acc[1][0] = __builtin_amdgcn_mfma_f32_16x16x32_bf16(a1, b0, acc[1][0], 0, 0, 0);
        acc[0][1] = __builtin_amdgcn_mfma_f32_16x16x32_bf16(a0, b1, acc[0][1], 0, 0, 0);
        acc[1][1] = __builtin_amdgcn_mfma_f32_16x16x32_bf16(a1, b1, acc[1][1], 0, 0, 0);
    }
    __syncthreads();
    for (int i = t; i < OD * 128 / 4; i += 256) {
        int base = i * 4;
        int n = base / 128, k = base % 128;
        float4 w = *(const float4*)(Wa + n * KA + 128 + k);
        *(us4*)&sW[n][k] = pk4(w);
    }
    __syncthreads();
    #pragma unroll
    for (int ks = 0; ks < 4; ++ks) {
        bf16x8 a0 = *(const bf16x8*)&sA[l15][128 + ks * 32 + koff];
        bf16x8 a1 = *(const bf16x8*)&sA[16 + l15][128 + ks * 32 + koff];
        bf16x8 b0 = *(const bf16x8*)&sW[w * 32 + l15][ks * 32 + koff];
        bf16x8 b1 = *(const bf16x8*)&sW[w * 32 + 16 + l15][ks * 32 + koff];
        acc[0][0] = __builtin_amdgcn_mfma_f32_16x16x32_bf16(a0, b0, acc[0][0], 0, 0, 0);
        acc[1][0] = __builtin_amdgcn_mfma_f32_16x16x32_bf16(a1, b0, acc[1][0], 0, 0, 0);
        acc[0][1] = __builtin_amdgcn_mfma_f32_16x16x32_bf16(a0, b1, acc[0][1], 0, 0, 0);
        acc[1][1] = __builtin_amdgcn_mfma_f32_16x16x32_bf16(a1, b1, acc[1][1], 0, 0, 0);
    }

    #pragma unroll
    for (int ai = 0; ai < 2; ++ai)
        #pragma unroll
        for (int r = 0; r < 4; ++r) {
            int nd = n0 + ai * 16 + 4 * lhi + r;
            #pragma unroll
            for (int bj = 0; bj < 2; ++bj) {
                int n = w * 32 + bj * 16 + l15;
                float v = acc[ai][bj][r] + ba[n];
                out[(size_t)nd * OD + n] = v > 0.f ? v : 0.f;
            }
        }
}

extern "C" void kernel_launch(void* const* d_in, const int* in_sizes, int n_in,
                              void* d_out, int out_size, void* d_ws, size_t ws_size,
                              hipStream_t stream) {
    const float* node  = (const float*)d_in[0];
    const float* edgef = (const float*)d_in[1];
    const int*   src   = (const int*)d_in[2];
    const int*   dst   = (const int*)d_in[3];
    const float* Wm    = (const float*)d_in[4];
    const float* bm    = (const float*)d_in[5];
    const float* Wa    = (const float*)d_in[6];
    const float* ba    = (const float*)d_in[7];
    float* out = (float*)d_out;

    // ws layout
    size_t o = 0;
    const size_t o_P    = o; o += (size_t)NN * OD * 2;          // 10.24 MB
    const size_t o_hn   = o; o += (size_t)NN * OD * 4;          // 20.48 MB
    const size_t o_eid  = o; o += (size_t)NE * 4;
    const size_t o_srcp = o; o += (size_t)NE * 4;
    const size_t o_dstp = o; o += (size_t)NE * 4;
    const size_t o_off  = o; o += ((size_t)(NN + 1) * 4 + 15) & ~(size_t)15;
    const size_t o_cur  = o; o += (size_t)NN * 4;
    const size_t o_bsum = o; o += 64 * 4;
    const size_t o_boff = o; o += 64 * 4;
    const size_t need   = o;                                     // ~38.9 MB

    char* ws = (char*)d_ws;

    if (ws_size >= need) {
        unsigned short* P  = (unsigned short*)(ws + o_P);
        float* hn  = (float*)(ws + o_hn);
        int* eid   = (int*)(ws + o_eid);
        int* srcp  = (int*)(ws + o_srcp);
        int* dstp  = (int*)(ws + o_dstp);
        int* off   = (int*)(ws + o_off);
        int* cur   = (int*)(ws + o_cur);
        int* bsum  = (int*)(ws + o_bsum);
        int* boff  = (int*)(ws + o_boff);

        hipMemsetAsync(cur, 0, (size_t)NN * 4, stream);
        hipMemsetAsync(hn, 0, (size_t)NN * OD * 4, stream);
        hist_kernel<<<(NE + 255) / 256, 256, 0, stream>>>(dst, cur);
        scanA_kernel<<<NB, 1024, 0, stream>>>(cur, off, bsum);
        scanB_kernel<<<1, 64, 0, stream>>>(bsum, boff, off);
        scanC_kernel<<<NB, 1024, 0, stream>>>(off, boff, cur);
        scatter_kernel<<<(NE + 255) / 256, 256, 0, stream>>>(dst, src, cur, eid, srcp, dstp);
        proj_kernel<<<NN / PT, 256, 0, stream>>>(node, Wm, P);
        msgagg_kernel<<<NE / QT, 256, 0, stream>>>(edgef, eid, srcp, dstp, P, Wm, bm, hn);
        apply_kernel<<<NN / AT, 256, 0, stream>>>(node, hn, Wa, ba, out);
    } else {
        const size_t hn_bytes = (size_t)NN * OD * 4;
        float* hn = (ws_size >= hn_bytes) ? (float*)d_ws : out;
        hipMemsetAsync(hn, 0, hn_bytes, stream);
        msg_kernel_atomic<<<NE / MT, 256, 0, stream>>>(node, edgef, src, dst, Wm, bm, hn);
        apply_kernel<<<NN / AT, 256, 0, stream>>>(node, hn, Wa, ba, out);
    }
}

// Round 5
// 213.858 us; speedup vs baseline: 2.5110x; 1.0401x over previous
//
#include <hip/hip_runtime.h>
#include <hip/hip_bf16.h>
#include <stdint.h>

#define NN 40000
#define NE 640000
#define ND 128
#define ED 64
#define OD 128
#define KM 192   // ND + ED
#define KA 256   // ND + OD
#define NB 40    // scan blocks (40*1024 >= NN)

typedef __attribute__((ext_vector_type(8))) short bf16x8;
typedef __attribute__((ext_vector_type(4))) float f32x4;
typedef __attribute__((ext_vector_type(4))) unsigned short us4;

__device__ __forceinline__ uint32_t pkbf2(float a, float b) {
    __hip_bfloat162 h = __float22bfloat162_rn(make_float2(a, b));
    union { __hip_bfloat162 h; uint32_t u; } cv; cv.h = h; return cv.u;
}
__device__ __forceinline__ unsigned short f2bf1(float f) {
    __hip_bfloat16 h = __float2bfloat16(f);
    union { __hip_bfloat16 h; unsigned short u; } cv; cv.h = h; return cv.u;
}
__device__ __forceinline__ us4 pk4(float4 v) {
    union { uint2 u; us4 s; } cv;
    cv.u.x = pkbf2(v.x, v.y);
    cv.u.y = pkbf2(v.z, v.w);
    return cv.s;
}
__device__ __forceinline__ bf16x8 pk8(float4 a, float4 b) {
    union { uint4 u; bf16x8 s; } cv;
    cv.u.x = pkbf2(a.x, a.y); cv.u.y = pkbf2(a.z, a.w);
    cv.u.z = pkbf2(b.x, b.y); cv.u.w = pkbf2(b.z, b.w);
    return cv.s;
}
__device__ __forceinline__ void st_bf4(unsigned short* p, float4 v) {
    uint2 r; r.x = pkbf2(v.x, v.y); r.y = pkbf2(v.z, v.w);
    *(uint2*)p = r;
}
__device__ __forceinline__ float b2f(unsigned short u) {
    union { uint32_t u; float f; } v; v.u = ((uint32_t)u) << 16; return v.f;
}

// ---------------- CSR build ----------------
__global__ void hist_kernel(const int* __restrict__ dst, int* __restrict__ cnt) {
    int e = blockIdx.x * blockDim.x + threadIdx.x;
    if (e < NE) atomicAdd(&cnt[dst[e]], 1);
}

// in-place per-block exclusive scan of cur[1024] chunk; bsum[b] = block total
__global__ __launch_bounds__(1024) void scanA_kernel(
    int* __restrict__ cur, int* __restrict__ bsum)
{
    __shared__ int wsum[16];
    const int t = threadIdx.x, b = blockIdx.x;
    const int idx = b * 1024 + t;
    int v = (idx < NN) ? cur[idx] : 0;
    int x = v;
    #pragma unroll
    for (int d = 1; d < 64; d <<= 1) {
        int y = __shfl_up(x, d, 64);
        if ((t & 63) >= d) x += y;
    }
    const int wid = t >> 6;
    if ((t & 63) == 63) wsum[wid] = x;
    __syncthreads();
    if (t < 16) {
        int s = wsum[t];
        #pragma unroll
        for (int d = 1; d < 16; d <<= 1) {
            int y = __shfl_up(s, d, 64);
            if (t >= d) s += y;
        }
        wsum[t] = s;
    }
    __syncthreads();
    int incl = x + (wid > 0 ? wsum[wid - 1] : 0);
    if (idx < NN) cur[idx] = incl - v;
    if (t == 1023) bsum[b] = incl;
}

// add prefix of block sums (computed in-kernel, b<=40 elems)
__global__ __launch_bounds__(1024) void scanC_kernel(
    int* __restrict__ cur, const int* __restrict__ bsum)
{
    __shared__ int sboff;
    const int t = threadIdx.x, b = blockIdx.x;
    if (t < 64) {
        int v = (t < b) ? bsum[t] : 0;
        #pragma unroll
        for (int d = 32; d > 0; d >>= 1) v += __shfl_down(v, d, 64);
        if (t == 0) sboff = v;
    }
    __syncthreads();
    const int idx = b * 1024 + t;
    if (idx < NN) cur[idx] += sboff;
}

__global__ void scatter_kernel(const int* __restrict__ dst, const int* __restrict__ src,
                               int* __restrict__ cur, int4* __restrict__ tri) {
    int e = blockIdx.x * blockDim.x + threadIdx.x;
    if (e < NE) {
        int s = src[e];
        int d = dst[e];
        int p = atomicAdd(&cur[d], 1);
        tri[p] = make_int4(e, s, d, 0);
    }
}

// ---------------- proj: P = node @ Wn^T (bf16 out, no bias) ----------------
#define PT 32
__global__ __launch_bounds__(256, 2) void proj_kernel(
    const float* __restrict__ node, const float* __restrict__ Wm,
    unsigned short* __restrict__ P)
{
    __shared__ unsigned short sW[OD][136];
    __shared__ unsigned short sA[PT][136];
    const int t = threadIdx.x, n0 = blockIdx.x * PT;
    {
        int el = t >> 3, sub = t & 7;
        const float* np = node + (size_t)(n0 + el) * ND + sub * 16;
        #pragma unroll
        for (int i = 0; i < 4; ++i) {
            float4 v = *(const float4*)(np + i * 4);
            *(us4*)&sA[el][sub * 16 + i * 4] = pk4(v);
        }
    }
    for (int i = t; i < OD * 128 / 4; i += 256) {
        int base = i * 4;
        int n = base / 128, k = base % 128;
        float4 wv = *(const float4*)(Wm + n * KM + k);
        *(us4*)&sW[n][k] = pk4(wv);
    }
    __syncthreads();

    const int w = t >> 6, lane = t & 63, l15 = lane & 15, lhi = lane >> 4;
    const int koff = lhi * 8;
    f32x4 acc[2][2] = {};
    #pragma unroll
    for (int ks = 0; ks < 4; ++ks) {
        bf16x8 a0 = *(const bf16x8*)&sA[l15][ks * 32 + koff];
        bf16x8 a1 = *(const bf16x8*)&sA[16 + l15][ks * 32 + koff];
        bf16x8 b0 = *(const bf16x8*)&sW[w * 32 + l15][ks * 32 + koff];
        bf16x8 b1 = *(const bf16x8*)&sW[w * 32 + 16 + l15][ks * 32 + koff];
        acc[0][0] = __builtin_amdgcn_mfma_f32_16x16x32_bf16(a0, b0, acc[0][0], 0, 0, 0);
        acc[1][0] = __builtin_amdgcn_mfma_f32_16x16x32_bf16(a1, b0, acc[1][0], 0, 0, 0);
        acc[0][1] = __builtin_amdgcn_mfma_f32_16x16x32_bf16(a0, b1, acc[0][1], 0, 0, 0);
        acc[1][1] = __builtin_amdgcn_mfma_f32_16x16x32_bf16(a1, b1, acc[1][1], 0, 0, 0);
    }
    #pragma unroll
    for (int ai = 0; ai < 2; ++ai)
        #pragma unroll
        for (int r = 0; r < 4; ++r) {
            int m = n0 + ai * 16 + 4 * lhi + r;
            #pragma unroll
            for (int bj = 0; bj < 2; ++bj) {
                int n = w * 32 + bj * 16 + l15;
                P[(size_t)m * OD + n] = f2bf1(acc[ai][bj][r]);
            }
        }
}

// ---------------- fused message + segmented aggregate (pipelined) ----------------
#define QT 64
#define MROW 148
#define GRID_MSG 2048

__global__ __launch_bounds__(256, 4) void msgagg_kernel(
    const float* __restrict__ edgef, const int4* __restrict__ tri,
    const unsigned short* __restrict__ P,
    const float* __restrict__ Wm, const float* __restrict__ bm,
    float* __restrict__ hn)
{
    __shared__ union {
        struct {
            unsigned short E[QT][72];    // 9216 B
            unsigned short Pp[QT][136];  // 17408 B
        } s;
        unsigned short m[QT][MROW];      // 18944 B
    } u;
    __shared__ int sD[QT];

    const int t = threadIdx.x;
    const int w = t >> 6, lane = t & 63, l15 = lane & 15, lhi = lane >> 4;
    const int row = t >> 2, s4 = t & 3;

    // B fragments in registers: We = Wm[:, 128:192)
    bf16x8 bw[2][2];
    #pragma unroll
    for (int bj = 0; bj < 2; ++bj) {
        int n = w * 32 + bj * 16 + l15;
        const float* wp = Wm + n * KM + ND;
        #pragma unroll
        for (int ks = 0; ks < 2; ++ks) {
            float4 x = *(const float4*)(wp + ks * 32 + lhi * 8);
            float4 y = *(const float4*)(wp + ks * 32 + lhi * 8 + 4);
            bw[ks][bj] = pk8(x, y);
        }
    }
    float bmv[2] = { bm[w * 32 + l15], bm[w * 32 + 16 + l15] };

    const int NT = NE / QT;
    int tile = blockIdx.x;
    if (tile >= NT) return;

    float4 rE0, rE1, rE2, rE3;
    uint4  rP0, rP1, rP2, rP3;
    int4 id, idn;

#define GATHER() do { \
        const float* ep_ = edgef + (size_t)id.x * ED + s4 * 16; \
        rE0 = *(const float4*)(ep_ + 0); \
        rE1 = *(const float4*)(ep_ + 4); \
        rE2 = *(const float4*)(ep_ + 8); \
        rE3 = *(const float4*)(ep_ + 12); \
        const uint4* pp_ = (const uint4*)(P + (size_t)id.y * OD) + s4 * 4; \
        rP0 = pp_[0]; rP1 = pp_[1]; rP2 = pp_[2]; rP3 = pp_[3]; \
    } while (0)

    id = tri[(size_t)tile * QT + row];
    GATHER();
    {
        int nx = tile + GRID_MSG;
        idn = tri[(size_t)(nx < NT ? nx : 0) * QT + row];
    }

    for (;;) {
        // ---- stage tile from registers ----
        st_bf4(&u.s.E[row][s4 * 16 +  0], rE0);
        st_bf4(&u.s.E[row][s4 * 16 +  4], rE1);
        st_bf4(&u.s.E[row][s4 * 16 +  8], rE2);
        st_bf4(&u.s.E[row][s4 * 16 + 12], rE3);
        *(uint4*)&u.s.Pp[row][s4 * 32 +  0] = rP0;
        *(uint4*)&u.s.Pp[row][s4 * 32 +  8] = rP1;
        *(uint4*)&u.s.Pp[row][s4 * 32 + 16] = rP2;
        *(uint4*)&u.s.Pp[row][s4 * 32 + 24] = rP3;
        if (s4 == 0) sD[row] = id.z;
        __syncthreads();

        // ---- issue next tile's gathers (overlap with compute below) ----
        const int next = tile + GRID_MSG;
        const bool more = next < NT;
        if (more) {
            id = idn;
            GATHER();
            int nx2 = next + GRID_MSG;
            idn = tri[(size_t)(nx2 < NT ? nx2 : 0) * QT + row];
        }

        // ---- MFMA ----
        f32x4 acc[4][2] = {};
        #pragma unroll
        for (int ks = 0; ks < 2; ++ks) {
            bf16x8 a[4];
            #pragma unroll
            for (int ai = 0; ai < 4; ++ai)
                a[ai] = *(const bf16x8*)&u.s.E[ai * 16 + l15][ks * 32 + lhi * 8];
            #pragma unroll
            for (int ai = 0; ai < 4; ++ai) {
                acc[ai][0] = __builtin_amdgcn_mfma_f32_16x16x32_bf16(a[ai], bw[ks][0], acc[ai][0], 0, 0, 0);
                acc[ai][1] = __builtin_amdgcn_mfma_f32_16x16x32_bf16(a[ai], bw[ks][1], acc[ai][1], 0, 0, 0);
            }
        }

        // ---- epilogue: relu(acc + bias + P) ----
        #pragma unroll
        for (int ai = 0; ai < 4; ++ai)
            #pragma unroll
            for (int r = 0; r < 4; ++r) {
                int m = ai * 16 + 4 * lhi + r;
                #pragma unroll
                for (int bj = 0; bj < 2; ++bj) {
                    int n = w * 32 + bj * 16 + l15;
                    float v = acc[ai][bj][r] + bmv[bj] + b2f(u.s.Pp[m][n]);
                    acc[ai][bj][r] = v > 0.f ? v : 0.f;
                }
            }
        __syncthreads();   // all E/Pp reads complete

        // ---- dump message tile to LDS (aliased) ----
        #pragma unroll
        for (int ai = 0; ai < 4; ++ai)
            #pragma unroll
            for (int r = 0; r < 4; ++r) {
                int m = ai * 16 + 4 * lhi + r;
                #pragma unroll
                for (int bj = 0; bj < 2; ++bj) {
                    int n = w * 32 + bj * 16 + l15;
                    u.m[m][n] = f2bf1(acc[ai][bj][r]);
                }
            }
        __syncthreads();

        // ---- segmented sum: 256 threads, two 32-row halves ----
        {
            const int half = t >> 7;        // 0 or 1
            const int c = t & 127;
            const int r0 = half * 32;
            int dprev = sD[r0];
            int start = r0;
            float accv = b2f(u.m[r0][c]);
            #pragma unroll 8
            for (int r = r0 + 1; r < r0 + 32; ++r) {
                int d = sD[r];              // wave-uniform
                float v = b2f(u.m[r][c]);
                if (d != dprev) {
                    float* dest = hn + (size_t)dprev * OD + c;
                    if (start > r0) *dest = accv;   // fully interior to this half
                    else atomicAdd(dest, accv);     // may span boundary
                    accv = v; dprev = d; start = r;
                } else {
                    accv += v;
                }
            }
            float* dest = hn + (size_t)dprev * OD + c;
            bool cont = (half == 0) ? (sD[32] == dprev) : true;
            if (!cont && start > r0) *dest = accv;
            else atomicAdd(dest, accv);
        }

        if (!more) break;
        tile = next;
        __syncthreads();   // segsum LDS reads done before next stage
    }
#undef GATHER
}

// ---------------- fallback atomic msg (ws too small) ----------------
#define MT 32
#define LK (KM + 8)
__global__ __launch_bounds__(256, 2) void msg_kernel_atomic(
    const float* __restrict__ node, const float* __restrict__ edgef,
    const int* __restrict__ src, const int* __restrict__ dst,
    const float* __restrict__ Wm, const float* __restrict__ bm,
    float* __restrict__ hn)
{
    __shared__ unsigned short sW[OD][LK];
    __shared__ unsigned short sA[MT][LK];

    const int t  = threadIdx.x;
    const int e0 = blockIdx.x * MT;

    for (int i = t; i < OD * KM / 4; i += 256) {
        int base = i * 4;
        int n = base / KM, k = base % KM;
        float4 w = *(const float4*)(Wm + n * KM + k);
        *(us4*)&sW[n][k] = pk4(w);
    }
    {
        int el = t >> 3, sub = t & 7;
        int s = src[e0 + el];
        const float* np = node + (size_t)s * ND + sub * 16;
        #pragma unroll
        for (int i = 0; i < 4; ++i) {
            float4 v = *(const float4*)(np + i * 4);
            *(us4*)&sA[el][sub * 16 + i * 4] = pk4(v);
        }
        const float* ep = edgef + (size_t)(e0 + el) * ED + sub * 8;
        #pragma unroll
        for (int i = 0; i < 2; ++i) {
            float4 v = *(const float4*)(ep + i * 4);
            *(us4*)&sA[el][ND + sub * 8 + i * 4] = pk4(v);
        }
    }
    __syncthreads();

    const int w = t >> 6, lane = t & 63, l15 = lane & 15, lhi = lane >> 4;
    const int koff = lhi * 8;
    f32x4 acc[2][2] = {};

    #pragma unroll
    for (int ks = 0; ks < 6; ++ks) {
        bf16x8 a0 = *(const bf16x8*)&sA[l15][ks * 32 + koff];
        bf16x8 a1 = *(const bf16x8*)&sA[16 + l15][ks * 32 + koff];
        bf16x8 b0 = *(const bf16x8*)&sW[w * 32 + l15][ks * 32 + koff];
        bf16x8 b1 = *(const bf16x8*)&sW[w * 32 + 16 + l15][ks * 32 + koff];
        acc[0][0] = __builtin_amdgcn_mfma_f32_16x16x32_bf16(a0, b0, acc[0][0], 0, 0, 0);
        acc[1][0] = __builtin_amdgcn_mfma_f32_16x16x32_bf16(a1, b0, acc[1][0], 0, 0, 0);
        acc[0][1] = __builtin_amdgcn_mfma_f32_16x16x32_bf16(a0, b1, acc[0][1], 0, 0, 0);
        acc[1][1] = __builtin_amdgcn_mfma_f32_16x16x32_bf16(a1, b1, acc[1][1], 0, 0, 0);
    }

    #pragma unroll
    for (int ai = 0; ai < 2; ++ai)
        #pragma unroll
        for (int r = 0; r < 4; ++r) {
            int el = ai * 16 + 4 * lhi + r;
            int d  = dst[e0 + el];
            float* hrow = hn + (size_t)d * OD;
            #pragma unroll
            for (int bj = 0; bj < 2; ++bj) {
                int n = w * 32 + bj * 16 + l15;
                float v = acc[ai][bj][r] + bm[n];
                v = v > 0.f ? v : 0.f;
                atomicAdd(hrow + n, v);
            }
        }
}

// ---------------- apply: relu([node | h_neigh] @ Wa^T + ba) ----------------
#define AT 32
#define LKA (KA + 8)
#define LKW (128 + 8)

__global__ __launch_bounds__(256, 2) void apply_kernel(
    const float* __restrict__ node, const float* __restrict__ hn,
    const float* __restrict__ Wa, const float* __restrict__ ba,
    float* __restrict__ out)
{
    __shared__ unsigned short sW[OD][LKW];
    __shared__ unsigned short sA[AT][LKA];

    const int t  = threadIdx.x;
    const int n0 = blockIdx.x * AT;

    {
        int el = t >> 3, sub = t & 7;
        const float* np = node + (size_t)(n0 + el) * ND + sub * 16;
        #pragma unroll
        for (int i = 0; i < 4; ++i) {
            float4 v = *(const float4*)(np + i * 4);
            *(us4*)&sA[el][sub * 16 + i * 4] = pk4(v);
        }
        const float* hp = hn + (size_t)(n0 + el) * OD + sub * 16;
        #pragma unroll
        for (int i = 0; i < 4; ++i) {
            float4 v = *(const float4*)(hp + i * 4);
            *(us4*)&sA[el][ND + sub * 16 + i * 4] = pk4(v);
        }
    }
    for (int i = t; i < OD * 128 / 4; i += 256) {
        int base = i * 4;
        int n = base / 128, k = base % 128;
        float4 w = *(const float4*)(Wa + n * KA + k);
        *(us4*)&sW[n][k] = pk4(w);
    }
    __syncthreads();

    const int w = t >> 6, lane = t & 63, l15 = lane & 15, lhi = lane >> 4;
    const int koff = lhi * 8;
    f32x4 acc[2][2] = {};

    #pragma unroll
    for (int ks = 0; ks < 4; ++ks) {
        bf16x8 a0 = *(const bf16x8*)&sA[l15][ks * 32 + koff];
        bf16x8 a1 = *(const bf16x8*)&sA[16 + l15][ks * 32 + koff];
        bf16x8 b0 = *(const bf16x8*)&sW[w * 32 + l15][ks * 32 + koff];
        bf16x8 b1 = *(const bf16x8*)&sW[w * 32 + 16 + l15][ks * 32 + koff];
        acc[0][0] = __builtin_amdgcn_mfma_f32_16x16x32_bf16(a0, b0, acc[0][0], 0, 0, 0);
        acc[1][0] = __builtin_amdgcn_mfma_f32_16x16x32_bf16(a1, b0, acc[1][0], 0, 0, 0);
        acc[0][1] = __builtin_amdgcn_mfma_f32_16x16x32_bf16(a0, b1, acc[0][1], 0, 0, 0);
        acc[1][1] = __builtin_amdgcn_mfma_f32_16x16x32_bf16(a1, b1, acc[1][1], 0, 0, 0);
    }
    __syncthreads();
    for (int i = t; i < OD * 128 / 4; i += 256) {
        int base = i * 4;
        int n = base / 128, k = base % 128;
        float4 w = *(const float4*)(Wa + n * KA + 128 + k);
        *(us4*)&sW[n][k] = pk4(w);
    }
    __syncthreads();
    #pragma unroll
    for (int ks = 0; ks < 4; ++ks) {
        bf16x8 a0 = *(const bf16x8*)&sA[l15][128 + ks * 32 + koff];
        bf16x8 a1 = *(const bf16x8*)&sA[16 + l15][128 + ks * 32 + koff];
        bf16x8 b0 = *(const bf16x8*)&sW[w * 32 + l15][ks * 32 + koff];
        bf16x8 b1 = *(const bf16x8*)&sW[w * 32 + 16 + l15][ks * 32 + koff];
        acc[0][0] = __builtin_amdgcn_mfma_f32_16x16x32_bf16(a0, b0, acc[0][0], 0, 0, 0);
        acc[1][0] = __builtin_amdgcn_mfma_f32_16x16x32_bf16(a1, b0, acc[1][0], 0, 0, 0);
        acc[0][1] = __builtin_amdgcn_mfma_f32_16x16x32_bf16(a0, b1, acc[0][1], 0, 0, 0);
        acc[1][1] = __builtin_amdgcn_mfma_f32_16x16x32_bf16(a1, b1, acc[1][1], 0, 0, 0);
    }

    #pragma unroll
    for (int ai = 0; ai < 2; ++ai)
        #pragma unroll
        for (int r = 0; r < 4; ++r) {
            int nd = n0 + ai * 16 + 4 * lhi + r;
            #pragma unroll
            for (int bj = 0; bj < 2; ++bj) {
                int n = w * 32 + bj * 16 + l15;
                float v = acc[ai][bj][r] + ba[n];
                out[(size_t)nd * OD + n] = v > 0.f ? v : 0.f;
            }
        }
}

extern "C" void kernel_launch(void* const* d_in, const int* in_sizes, int n_in,
                              void* d_out, int out_size, void* d_ws, size_t ws_size,
                              hipStream_t stream) {
    const float* node  = (const float*)d_in[0];
    const float* edgef = (const float*)d_in[1];
    const int*   src   = (const int*)d_in[2];
    const int*   dst   = (const int*)d_in[3];
    const float* Wm    = (const float*)d_in[4];
    const float* bm    = (const float*)d_in[5];
    const float* Wa    = (const float*)d_in[6];
    const float* ba    = (const float*)d_in[7];
    float* out = (float*)d_out;

    // ws layout
    size_t o = 0;
    const size_t o_P    = o; o += (size_t)NN * OD * 2;      // 10.24 MB
    const size_t o_hn   = o; o += (size_t)NN * OD * 4;      // 20.48 MB
    const size_t o_tri  = o; o += (size_t)NE * 16;          // 10.24 MB
    const size_t o_cur  = o; o += (size_t)NN * 4;           // 160 KB
    const size_t o_bsum = o; o += 64 * 4;
    const size_t need   = o;                                 // ~41.1 MB

    char* ws = (char*)d_ws;

    if (ws_size >= need) {
        unsigned short* P  = (unsigned short*)(ws + o_P);
        float* hn   = (float*)(ws + o_hn);
        int4*  tri  = (int4*)(ws + o_tri);
        int*   cur  = (int*)(ws + o_cur);
        int*   bsum = (int*)(ws + o_bsum);

        hipMemsetAsync(cur, 0, (size_t)NN * 4, stream);
        hipMemsetAsync(hn, 0, (size_t)NN * OD * 4, stream);
        hist_kernel<<<(NE + 255) / 256, 256, 0, stream>>>(dst, cur);
        scanA_kernel<<<NB, 1024, 0, stream>>>(cur, bsum);
        scanC_kernel<<<NB, 1024, 0, stream>>>(cur, bsum);
        scatter_kernel<<<(NE + 255) / 256, 256, 0, stream>>>(dst, src, cur, tri);
        proj_kernel<<<NN / PT, 256, 0, stream>>>(node, Wm, P);
        msgagg_kernel<<<GRID_MSG, 256, 0, stream>>>(edgef, tri, P, Wm, bm, hn);
        apply_kernel<<<NN / AT, 256, 0, stream>>>(node, hn, Wa, ba, out);
    } else {
        const size_t hn_bytes = (size_t)NN * OD * 4;
        float* hn = (ws_size >= hn_bytes) ? (float*)d_ws : out;
        hipMemsetAsync(hn, 0, hn_bytes, stream);
        msg_kernel_atomic<<<NE / MT, 256, 0, stream>>>(node, edgef, src, dst, Wm, bm, hn);
        apply_kernel<<<NN / AT, 256, 0, stream>>>(node, hn, Wa, ba, out);
    }
}